// Round 6
// baseline (118.944 us; speedup 1.0000x reference)
//
#include <hip/hip_runtime.h>

#define NROW 200000
#define RDIM 32
#define BATCH 131072
#define STEP 0.01f
#define CAP 8   // bucket capacity; Poisson(0.655) tail beyond 8 ~ 3e-8/row

// ===========================================================================
// FAST PATH ws layout (43.4 MB):
//   cnt    int[3*NROW]          (memset 0)
//   head   int[3*NROW]          (memset 0xFF -> -1; overflow chains only)
//   nxt    int[3*BATCH]
//   bucket int[3*NROW*CAP]
//   scal   float2[BATCH]        (A = ki - phi*wi, wi)
//   Lp     float[BATCH*32]      (L_r * g0*g1*g2)
// ===========================================================================

// Merged precompute + bucket build. 8 lanes per batch element, float4 I/O.
__global__ __launch_bounds__(256) void em_pre_bkt(
    const float* __restrict__ U0, const float* __restrict__ U1,
    const float* __restrict__ U2, const float* __restrict__ L,
    const float* __restrict__ bv, const int* __restrict__ be,
    int* __restrict__ cnt, int* __restrict__ head, int* __restrict__ nxt,
    int* __restrict__ bucket, float2* __restrict__ scal, float* __restrict__ LpBuf)
{
    int tid = blockIdx.x * blockDim.x + threadIdx.x;
    int i   = tid >> 3;          // batch element
    int sub = tid & 7;           // 4-float slot
    if (i >= BATCH) return;

    int e0 = be[i * 3 + 0];
    int e1 = be[i * 3 + 1];
    int e2 = be[i * 3 + 2];

    float4 g0 = *(const float4*)(U0 + (size_t)e0 * RDIM + sub * 4);
    float4 g1 = *(const float4*)(U1 + (size_t)e1 * RDIM + sub * 4);
    float4 g2 = *(const float4*)(U2 + (size_t)e2 * RDIM + sub * 4);
    float4 Lv = *(const float4*)(L + sub * 4);

    float4 Lp;
    Lp.x = Lv.x * g0.x * g1.x * g2.x;
    Lp.y = Lv.y * g0.y * g1.y * g2.y;
    Lp.z = Lv.z * g0.z * g1.z * g2.z;
    Lp.w = Lv.w * g0.w * g1.w * g2.w;

    float phi = (Lp.x + Lp.y) + (Lp.z + Lp.w);
    phi += __shfl_xor(phi, 1);
    phi += __shfl_xor(phi, 2);
    phi += __shfl_xor(phi, 4);

    float wi = 0.5f / phi * tanhf(0.5f * phi);

    *(float4*)(LpBuf + (size_t)i * RDIM + sub * 4) = Lp;

    if (sub == 0) {
        float A = (bv[i] - 0.5f) - phi * wi;
        scal[i] = make_float2(A, wi);
    }
    if (sub < 3) {
        int row = (sub == 0) ? e0 : (sub == 1) ? e1 : e2;
        int rid = sub * NROW + row;
        int slot = atomicAdd(&cnt[rid], 1);
        if (slot < CAP) {
            bucket[(size_t)rid * CAP + slot] = i;
        } else {
            int idx = i * 3 + sub;
            nxt[idx] = atomicExch(&head[rid], idx);
        }
    }
}

// 8 lanes per (d,row). Bucket loop = independent loads (MLP), float4 I/O.
__global__ __launch_bounds__(256) void em_apply_bkt(
    const float* __restrict__ U0, const float* __restrict__ U1,
    const float* __restrict__ U2,
    const float* __restrict__ S0, const float* __restrict__ S1,
    const float* __restrict__ S2,
    const float* __restrict__ T0, const float* __restrict__ T1,
    const float* __restrict__ T2,
    const int* __restrict__ cnt, const int* __restrict__ head,
    const int* __restrict__ nxt, const int* __restrict__ bucket,
    const float2* __restrict__ scal, const float* __restrict__ LpBuf,
    float* __restrict__ out)
{
    int tid = blockIdx.x * blockDim.x + threadIdx.x;
    int rid = tid >> 3;          // global row id in [0, 3*NROW)
    int sub = tid & 7;
    if (rid >= 3 * NROW) return;

    int d   = rid / NROW;        // uniform per block (NROW % 32 == 0)
    int row = rid - d * NROW;

    const float* Ud   = (d == 0) ? U0 : (d == 1) ? U1 : U2;
    const float* Ssrc = (d == 0) ? S0 : (d == 1) ? S1 : S2;
    const float* Tsrc = (d == 0) ? T0 : (d == 1) ? T1 : T2;

    size_t roff = (size_t)row * RDIM + sub * 4;
    float4 s_in = *(const float4*)(Ssrc + roff);
    float4 t_in = *(const float4*)(Tsrc + roff);

    int    n  = cnt[rid];
    float4 oS = s_in;
    float4 oT = t_in;

    if (n > 0) {   // uniform across the 8-lane subgroup
        float4 gd = *(const float4*)(Ud + roff);
        float4 rg;
        rg.x = __builtin_amdgcn_rcpf(gd.x);   // gd in [0.05,1] — safe
        rg.y = __builtin_amdgcn_rcpf(gd.y);
        rg.z = __builtin_amdgcn_rcpf(gd.z);
        rg.w = __builtin_amdgcn_rcpf(gd.w);

        float4 sa = make_float4(0.f, 0.f, 0.f, 0.f);
        float4 ta = make_float4(0.f, 0.f, 0.f, 0.f);

        const int* bk = bucket + (size_t)rid * CAP;
        int nb = (n < CAP) ? n : CAP;
        for (int j = 0; j < nb; ++j) {
            int e = bk[j];
            float2 aw = scal[e];
            float4 Lp = *(const float4*)(LpBuf + (size_t)e * RDIM + sub * 4);
            float cx = Lp.x * rg.x, cy = Lp.y * rg.y,
                  cz = Lp.z * rg.z, cw = Lp.w * rg.w;
            sa.x += aw.y * cx * cx;  sa.y += aw.y * cy * cy;
            sa.z += aw.y * cz * cz;  sa.w += aw.y * cw * cw;
            ta.x += (aw.x + aw.y * Lp.x) * cx;
            ta.y += (aw.x + aw.y * Lp.y) * cy;
            ta.z += (aw.x + aw.y * Lp.z) * cz;
            ta.w += (aw.x + aw.y * Lp.w) * cw;
        }
        if (n > CAP) {   // essentially never taken; correctness only
            int t = head[rid];
            while (t != -1) {
                int e = t / 3;
                float2 aw = scal[e];
                float4 Lp = *(const float4*)(LpBuf + (size_t)e * RDIM + sub * 4);
                float cx = Lp.x * rg.x, cy = Lp.y * rg.y,
                      cz = Lp.z * rg.z, cw = Lp.w * rg.w;
                sa.x += aw.y * cx * cx;  sa.y += aw.y * cy * cy;
                sa.z += aw.y * cz * cz;  sa.w += aw.y * cw * cw;
                ta.x += (aw.x + aw.y * Lp.x) * cx;
                ta.y += (aw.x + aw.y * Lp.y) * cy;
                ta.z += (aw.x + aw.y * Lp.z) * cz;
                ta.w += (aw.x + aw.y * Lp.w) * cw;
                t = nxt[t];
            }
        }
        oS.x = (1.0f - STEP) * s_in.x + STEP * sa.x;
        oS.y = (1.0f - STEP) * s_in.y + STEP * sa.y;
        oS.z = (1.0f - STEP) * s_in.z + STEP * sa.z;
        oS.w = (1.0f - STEP) * s_in.w + STEP * sa.w;
        oT.x = (1.0f - STEP) * t_in.x + STEP * ta.x;
        oT.y = (1.0f - STEP) * t_in.y + STEP * ta.y;
        oT.z = (1.0f - STEP) * t_in.z + STEP * ta.z;
        oT.w = (1.0f - STEP) * t_in.w + STEP * ta.w;
    }

    size_t offS = ((size_t)d * NROW + row) * RDIM + sub * 4;
    *(float4*)(out + offS) = oS;
    *(float4*)(out + (size_t)3 * NROW * RDIM + offS) = oT;
}

// ===========================================================================
// FALLBACK (Round-5 chain version) — used only if ws too small for buckets
// ===========================================================================
__global__ __launch_bounds__(256) void em_pre(
    const float* __restrict__ U0, const float* __restrict__ U1,
    const float* __restrict__ U2, const float* __restrict__ L,
    const float* __restrict__ bv, const int* __restrict__ be,
    int* __restrict__ head, int* __restrict__ nxt,
    float2* __restrict__ scal, float* __restrict__ LpBuf)
{
    int tid = blockIdx.x * blockDim.x + threadIdx.x;
    int i   = tid >> 3;
    int sub = tid & 7;
    if (i >= BATCH) return;

    int e0 = be[i * 3 + 0];
    int e1 = be[i * 3 + 1];
    int e2 = be[i * 3 + 2];

    float4 g0 = *(const float4*)(U0 + (size_t)e0 * RDIM + sub * 4);
    float4 g1 = *(const float4*)(U1 + (size_t)e1 * RDIM + sub * 4);
    float4 g2 = *(const float4*)(U2 + (size_t)e2 * RDIM + sub * 4);
    float4 Lv = *(const float4*)(L + sub * 4);

    float4 Lp;
    Lp.x = Lv.x * g0.x * g1.x * g2.x;
    Lp.y = Lv.y * g0.y * g1.y * g2.y;
    Lp.z = Lv.z * g0.z * g1.z * g2.z;
    Lp.w = Lv.w * g0.w * g1.w * g2.w;

    float phi = (Lp.x + Lp.y) + (Lp.z + Lp.w);
    phi += __shfl_xor(phi, 1);
    phi += __shfl_xor(phi, 2);
    phi += __shfl_xor(phi, 4);

    float wi = 0.5f / phi * tanhf(0.5f * phi);

    *(float4*)(LpBuf + (size_t)i * RDIM + sub * 4) = Lp;

    if (sub == 0) {
        float A = (bv[i] - 0.5f) - phi * wi;
        scal[i] = make_float2(A, wi);
    }
    if (sub < 3) {
        int row = (sub == 0) ? e0 : (sub == 1) ? e1 : e2;
        int idx = i * 3 + sub;
        nxt[idx] = atomicExch(&head[sub * NROW + row], idx);
    }
}

__global__ __launch_bounds__(256) void em_apply_vec(
    const float* __restrict__ U0, const float* __restrict__ U1,
    const float* __restrict__ U2,
    const float* __restrict__ S0, const float* __restrict__ S1,
    const float* __restrict__ S2,
    const float* __restrict__ T0, const float* __restrict__ T1,
    const float* __restrict__ T2,
    const int* __restrict__ head, const int* __restrict__ nxt,
    const float2* __restrict__ scal, const float* __restrict__ LpBuf,
    float* __restrict__ out)
{
    int tid = blockIdx.x * blockDim.x + threadIdx.x;
    int rid = tid >> 3;
    int sub = tid & 7;
    if (rid >= 3 * NROW) return;

    int d   = rid / NROW;
    int row = rid - d * NROW;

    const float* Ud   = (d == 0) ? U0 : (d == 1) ? U1 : U2;
    const float* Ssrc = (d == 0) ? S0 : (d == 1) ? S1 : S2;
    const float* Tsrc = (d == 0) ? T0 : (d == 1) ? T1 : T2;

    size_t roff = (size_t)row * RDIM + sub * 4;
    float4 s_in = *(const float4*)(Ssrc + roff);
    float4 t_in = *(const float4*)(Tsrc + roff);

    int    t  = head[rid];
    float4 oS = s_in;
    float4 oT = t_in;

    if (t != -1) {
        float4 gd = *(const float4*)(Ud + roff);
        float4 rg;
        rg.x = __builtin_amdgcn_rcpf(gd.x);
        rg.y = __builtin_amdgcn_rcpf(gd.y);
        rg.z = __builtin_amdgcn_rcpf(gd.z);
        rg.w = __builtin_amdgcn_rcpf(gd.w);

        float4 sa = make_float4(0.f, 0.f, 0.f, 0.f);
        float4 ta = make_float4(0.f, 0.f, 0.f, 0.f);
        while (t != -1) {
            int e = t / 3;
            float2 aw = scal[e];
            float4 Lp = *(const float4*)(LpBuf + (size_t)e * RDIM + sub * 4);
            float cx = Lp.x * rg.x, cy = Lp.y * rg.y,
                  cz = Lp.z * rg.z, cw = Lp.w * rg.w;
            sa.x += aw.y * cx * cx;  sa.y += aw.y * cy * cy;
            sa.z += aw.y * cz * cz;  sa.w += aw.y * cw * cw;
            ta.x += (aw.x + aw.y * Lp.x) * cx;
            ta.y += (aw.x + aw.y * Lp.y) * cy;
            ta.z += (aw.x + aw.y * Lp.z) * cz;
            ta.w += (aw.x + aw.y * Lp.w) * cw;
            t = nxt[t];
        }
        oS.x = (1.0f - STEP) * s_in.x + STEP * sa.x;
        oS.y = (1.0f - STEP) * s_in.y + STEP * sa.y;
        oS.z = (1.0f - STEP) * s_in.z + STEP * sa.z;
        oS.w = (1.0f - STEP) * s_in.w + STEP * sa.w;
        oT.x = (1.0f - STEP) * t_in.x + STEP * ta.x;
        oT.y = (1.0f - STEP) * t_in.y + STEP * ta.y;
        oT.z = (1.0f - STEP) * t_in.z + STEP * ta.z;
        oT.w = (1.0f - STEP) * t_in.w + STEP * ta.w;
    }

    size_t offS = ((size_t)d * NROW + row) * RDIM + sub * 4;
    *(float4*)(out + offS) = oS;
    *(float4*)(out + (size_t)3 * NROW * RDIM + offS) = oT;
}

// ===========================================================================
extern "C" void kernel_launch(void* const* d_in, const int* in_sizes, int n_in,
                              void* d_out, int out_size, void* d_ws, size_t ws_size,
                              hipStream_t stream)
{
    // setup_inputs() insertion order: U0,S0,T0, U1,S1,T1, U2,S2,T2, L, bv, be
    const float* U0 = (const float*)d_in[0];
    const float* S0 = (const float*)d_in[1];
    const float* T0 = (const float*)d_in[2];
    const float* U1 = (const float*)d_in[3];
    const float* S1 = (const float*)d_in[4];
    const float* T1 = (const float*)d_in[5];
    const float* U2 = (const float*)d_in[6];
    const float* S2 = (const float*)d_in[7];
    const float* T2 = (const float*)d_in[8];
    const float* L  = (const float*)d_in[9];
    const float* bv = (const float*)d_in[10];
    const int*   be = (const int*)d_in[11];

    float* out = (float*)d_out;

    const size_t rows3  = (size_t)3 * NROW;
    const size_t nxt_n  = (size_t)3 * BATCH;
    const size_t bkt_n  = rows3 * CAP;

    const size_t ints_fast = rows3 /*cnt*/ + rows3 /*head*/ + nxt_n + bkt_n;
    const size_t ws_fast   = ints_fast * sizeof(int)
                           + (size_t)BATCH * sizeof(float2)
                           + (size_t)BATCH * RDIM * sizeof(float);   // ~43.4 MB
    const size_t ws_mid    = (rows3 + nxt_n) * sizeof(int)
                           + (size_t)BATCH * sizeof(float2)
                           + (size_t)BATCH * RDIM * sizeof(float);   // ~21.8 MB

    if (ws_size >= ws_fast) {
        // ---- fast path: bucketed CSR ----
        int*    cnt    = (int*)d_ws;
        int*    head_  = cnt + rows3;
        int*    nxt    = head_ + rows3;
        int*    bucket = nxt + nxt_n;
        float2* scal   = (float2*)(bucket + bkt_n);
        float*  LpBuf  = (float*)(scal + BATCH);

        hipMemsetAsync(cnt, 0, rows3 * sizeof(int), stream);
        hipMemsetAsync(head_, 0xFF, rows3 * sizeof(int), stream);

        int pblocks = (BATCH * 8 + 255) / 256;    // 4096
        em_pre_bkt<<<pblocks, 256, 0, stream>>>(U0, U1, U2, L, bv, be,
                                                cnt, head_, nxt, bucket,
                                                scal, LpBuf);

        long athreads = 3L * NROW * 8;            // 4.8M
        int  ablocks  = (int)((athreads + 255) / 256);  // 18750
        em_apply_bkt<<<ablocks, 256, 0, stream>>>(U0, U1, U2, S0, S1, S2,
                                                  T0, T1, T2, cnt, head_, nxt,
                                                  bucket, scal, LpBuf, out);
    } else if (ws_size >= ws_mid) {
        // ---- fallback: round-5 linked-list version ----
        int*    head_ = (int*)d_ws;
        int*    nxt   = head_ + rows3;
        float2* scal  = (float2*)(nxt + nxt_n);
        float*  LpBuf = (float*)(scal + BATCH);

        hipMemsetAsync(head_, 0xFF, rows3 * sizeof(int), stream);

        int pblocks = (BATCH * 8 + 255) / 256;
        em_pre<<<pblocks, 256, 0, stream>>>(U0, U1, U2, L, bv, be,
                                            head_, nxt, scal, LpBuf);

        long athreads = 3L * NROW * 8;
        int  ablocks  = (int)((athreads + 255) / 256);
        em_apply_vec<<<ablocks, 256, 0, stream>>>(U0, U1, U2, S0, S1, S2,
                                                  T0, T1, T2, head_, nxt,
                                                  scal, LpBuf, out);
    }
    // (ws_size < 21.8 MB is not expected on this harness)
}

// Round 7
// 109.705 us; speedup vs baseline: 1.0842x; 1.0842x over previous
//
#include <hip/hip_runtime.h>

#define NROW 200000
#define RDIM 32
#define BATCH 131072
#define STEP 0.01f
#define CAP 8   // bucket capacity; Poisson(0.655) tail beyond 8 ~ 3e-8/row

// ===========================================================================
// FAST PATH ws layout (~43.4 MB), all 8B-aligned:
//   cnt    int[3*NROW]      \ one contiguous memset(0)
//   head   int[3*NROW]      /  (head uses idx+1 encoding; 0 = empty)
//   nxt    int[3*BATCH]
//   bucket int[3*NROW*CAP]
//   scal   float2[BATCH]    (A = ki - phi*wi, wi)
//   Lp     float[BATCH*32]  (L_r * g0*g1*g2)
// ===========================================================================

// Merged precompute + bucket build. 8 lanes per batch element, float4 I/O.
__global__ __launch_bounds__(256) void em_pre_bkt(
    const float* __restrict__ U0, const float* __restrict__ U1,
    const float* __restrict__ U2, const float* __restrict__ L,
    const float* __restrict__ bv, const int* __restrict__ be,
    int* __restrict__ cnt, int* __restrict__ head, int* __restrict__ nxt,
    int* __restrict__ bucket, float2* __restrict__ scal, float* __restrict__ LpBuf)
{
    int tid = blockIdx.x * blockDim.x + threadIdx.x;
    int i   = tid >> 3;          // batch element
    int sub = tid & 7;           // 4-float slot
    if (i >= BATCH) return;

    int e0 = be[i * 3 + 0];
    int e1 = be[i * 3 + 1];
    int e2 = be[i * 3 + 2];

    float4 g0 = *(const float4*)(U0 + (size_t)e0 * RDIM + sub * 4);
    float4 g1 = *(const float4*)(U1 + (size_t)e1 * RDIM + sub * 4);
    float4 g2 = *(const float4*)(U2 + (size_t)e2 * RDIM + sub * 4);
    float4 Lv = *(const float4*)(L + sub * 4);

    float4 Lp;
    Lp.x = Lv.x * g0.x * g1.x * g2.x;
    Lp.y = Lv.y * g0.y * g1.y * g2.y;
    Lp.z = Lv.z * g0.z * g1.z * g2.z;
    Lp.w = Lv.w * g0.w * g1.w * g2.w;

    float phi = (Lp.x + Lp.y) + (Lp.z + Lp.w);
    phi += __shfl_xor(phi, 1);
    phi += __shfl_xor(phi, 2);
    phi += __shfl_xor(phi, 4);

    float wi = 0.5f / phi * tanhf(0.5f * phi);

    *(float4*)(LpBuf + (size_t)i * RDIM + sub * 4) = Lp;

    if (sub == 0) {
        float A = (bv[i] - 0.5f) - phi * wi;
        scal[i] = make_float2(A, wi);
    }
    if (sub < 3) {
        int row = (sub == 0) ? e0 : (sub == 1) ? e1 : e2;
        int rid = sub * NROW + row;
        int slot = atomicAdd(&cnt[rid], 1);
        if (slot < CAP) {
            bucket[(size_t)rid * CAP + slot] = i;
        } else {
            int idx = i * 3 + sub;                       // idx+1 encoding
            nxt[idx] = atomicExch(&head[rid], idx + 1);
        }
    }
}

// 8 lanes per (d,row). Branchless burst-issue: all gathers in flight at once.
__global__ __launch_bounds__(256) void em_apply_mlp(
    const float* __restrict__ U0, const float* __restrict__ U1,
    const float* __restrict__ U2,
    const float* __restrict__ S0, const float* __restrict__ S1,
    const float* __restrict__ S2,
    const float* __restrict__ T0, const float* __restrict__ T1,
    const float* __restrict__ T2,
    const int* __restrict__ cnt, const int* __restrict__ head,
    const int* __restrict__ nxt, const int* __restrict__ bucket,
    const float2* __restrict__ scal, const float* __restrict__ LpBuf,
    float* __restrict__ out)
{
    int tid = blockIdx.x * blockDim.x + threadIdx.x;
    int rid = tid >> 3;          // global row id in [0, 3*NROW)
    int sub = tid & 7;
    if (rid >= 3 * NROW) return;

    int d   = rid / NROW;        // uniform per block (NROW % 32 == 0)
    int row = rid - d * NROW;

    const float* Ud   = (d == 0) ? U0 : (d == 1) ? U1 : U2;
    const float* Ssrc = (d == 0) ? S0 : (d == 1) ? S1 : S2;
    const float* Tsrc = (d == 0) ? T0 : (d == 1) ? T1 : T2;

    size_t roff = (size_t)row * RDIM + sub * 4;

    // --- burst: independent loads, no control deps between them ---
    int    n    = cnt[rid];
    int4   bk   = *(const int4*)(bucket + (size_t)rid * CAP);  // parallel w/ cnt
    float4 s_in = *(const float4*)(Ssrc + roff);
    float4 t_in = *(const float4*)(Tsrc + roff);

    // clamp unused entries to 0 (line 0 stays L1-hot); mask via zeroed weights
    int i0 = (n > 0) ? bk.x : 0;
    int i1 = (n > 1) ? bk.y : 0;
    int i2 = (n > 2) ? bk.z : 0;
    int i3 = (n > 3) ? bk.w : 0;

    float2 aw0 = scal[i0], aw1 = scal[i1], aw2 = scal[i2], aw3 = scal[i3];
    float4 p0 = *(const float4*)(LpBuf + (size_t)i0 * RDIM + sub * 4);
    float4 p1 = *(const float4*)(LpBuf + (size_t)i1 * RDIM + sub * 4);
    float4 p2 = *(const float4*)(LpBuf + (size_t)i2 * RDIM + sub * 4);
    float4 p3 = *(const float4*)(LpBuf + (size_t)i3 * RDIM + sub * 4);

    if (n <= 1) { aw1.x = 0.f; aw1.y = 0.f; }
    if (n <= 2) { aw2.x = 0.f; aw2.y = 0.f; }
    if (n <= 3) { aw3.x = 0.f; aw3.y = 0.f; }

    float4 rg = make_float4(0.f, 0.f, 0.f, 0.f);
    if (n > 0) {
        float4 gd = *(const float4*)(Ud + roff);
        rg.x = __builtin_amdgcn_rcpf(gd.x);   // gd in [0.05,1] — safe
        rg.y = __builtin_amdgcn_rcpf(gd.y);
        rg.z = __builtin_amdgcn_rcpf(gd.z);
        rg.w = __builtin_amdgcn_rcpf(gd.w);
    }

    float4 sa = make_float4(0.f, 0.f, 0.f, 0.f);
    float4 ta = make_float4(0.f, 0.f, 0.f, 0.f);

    #define ACC(AW, P)                                                  \
    {                                                                   \
        float cx = (P).x * rg.x, cy = (P).y * rg.y,                     \
              cz = (P).z * rg.z, cw = (P).w * rg.w;                     \
        sa.x += (AW).y * cx * cx;  sa.y += (AW).y * cy * cy;            \
        sa.z += (AW).y * cz * cz;  sa.w += (AW).y * cw * cw;            \
        ta.x += ((AW).x + (AW).y * (P).x) * cx;                         \
        ta.y += ((AW).x + (AW).y * (P).y) * cy;                         \
        ta.z += ((AW).x + (AW).y * (P).z) * cz;                         \
        ta.w += ((AW).x + (AW).y * (P).w) * cw;                         \
    }

    ACC(aw0, p0) ACC(aw1, p1) ACC(aw2, p2) ACC(aw3, p3)

    if (n > 4) {   // cold: ~6e-4 of rows
        int nb = (n < CAP) ? n : CAP;
        for (int j = 4; j < nb; ++j) {
            int e = bucket[(size_t)rid * CAP + j];
            float2 aw = scal[e];
            float4 P  = *(const float4*)(LpBuf + (size_t)e * RDIM + sub * 4);
            ACC(aw, P)
        }
        if (n > CAP) {   // essentially never; correctness only
            int t = head[rid];
            while (t != 0) {
                int idx = t - 1;
                int e = idx / 3;
                float2 aw = scal[e];
                float4 P  = *(const float4*)(LpBuf + (size_t)e * RDIM + sub * 4);
                ACC(aw, P)
                t = nxt[idx];
            }
        }
    }
    #undef ACC

    bool touched = (n > 0);
    float4 oS, oT;
    oS.x = touched ? (1.0f - STEP) * s_in.x + STEP * sa.x : s_in.x;
    oS.y = touched ? (1.0f - STEP) * s_in.y + STEP * sa.y : s_in.y;
    oS.z = touched ? (1.0f - STEP) * s_in.z + STEP * sa.z : s_in.z;
    oS.w = touched ? (1.0f - STEP) * s_in.w + STEP * sa.w : s_in.w;
    oT.x = touched ? (1.0f - STEP) * t_in.x + STEP * ta.x : t_in.x;
    oT.y = touched ? (1.0f - STEP) * t_in.y + STEP * ta.y : t_in.y;
    oT.z = touched ? (1.0f - STEP) * t_in.z + STEP * ta.z : t_in.z;
    oT.w = touched ? (1.0f - STEP) * t_in.w + STEP * ta.w : t_in.w;

    size_t offS = ((size_t)d * NROW + row) * RDIM + sub * 4;
    *(float4*)(out + offS) = oS;
    *(float4*)(out + (size_t)3 * NROW * RDIM + offS) = oT;
}

// ===========================================================================
// FALLBACK (Round-5 chain version) — used only if ws too small for buckets
// ===========================================================================
__global__ __launch_bounds__(256) void em_pre(
    const float* __restrict__ U0, const float* __restrict__ U1,
    const float* __restrict__ U2, const float* __restrict__ L,
    const float* __restrict__ bv, const int* __restrict__ be,
    int* __restrict__ head, int* __restrict__ nxt,
    float2* __restrict__ scal, float* __restrict__ LpBuf)
{
    int tid = blockIdx.x * blockDim.x + threadIdx.x;
    int i   = tid >> 3;
    int sub = tid & 7;
    if (i >= BATCH) return;

    int e0 = be[i * 3 + 0];
    int e1 = be[i * 3 + 1];
    int e2 = be[i * 3 + 2];

    float4 g0 = *(const float4*)(U0 + (size_t)e0 * RDIM + sub * 4);
    float4 g1 = *(const float4*)(U1 + (size_t)e1 * RDIM + sub * 4);
    float4 g2 = *(const float4*)(U2 + (size_t)e2 * RDIM + sub * 4);
    float4 Lv = *(const float4*)(L + sub * 4);

    float4 Lp;
    Lp.x = Lv.x * g0.x * g1.x * g2.x;
    Lp.y = Lv.y * g0.y * g1.y * g2.y;
    Lp.z = Lv.z * g0.z * g1.z * g2.z;
    Lp.w = Lv.w * g0.w * g1.w * g2.w;

    float phi = (Lp.x + Lp.y) + (Lp.z + Lp.w);
    phi += __shfl_xor(phi, 1);
    phi += __shfl_xor(phi, 2);
    phi += __shfl_xor(phi, 4);

    float wi = 0.5f / phi * tanhf(0.5f * phi);

    *(float4*)(LpBuf + (size_t)i * RDIM + sub * 4) = Lp;

    if (sub == 0) {
        float A = (bv[i] - 0.5f) - phi * wi;
        scal[i] = make_float2(A, wi);
    }
    if (sub < 3) {
        int row = (sub == 0) ? e0 : (sub == 1) ? e1 : e2;
        int idx = i * 3 + sub;
        nxt[idx] = atomicExch(&head[sub * NROW + row], idx + 1);
    }
}

__global__ __launch_bounds__(256) void em_apply_vec(
    const float* __restrict__ U0, const float* __restrict__ U1,
    const float* __restrict__ U2,
    const float* __restrict__ S0, const float* __restrict__ S1,
    const float* __restrict__ S2,
    const float* __restrict__ T0, const float* __restrict__ T1,
    const float* __restrict__ T2,
    const int* __restrict__ head, const int* __restrict__ nxt,
    const float2* __restrict__ scal, const float* __restrict__ LpBuf,
    float* __restrict__ out)
{
    int tid = blockIdx.x * blockDim.x + threadIdx.x;
    int rid = tid >> 3;
    int sub = tid & 7;
    if (rid >= 3 * NROW) return;

    int d   = rid / NROW;
    int row = rid - d * NROW;

    const float* Ud   = (d == 0) ? U0 : (d == 1) ? U1 : U2;
    const float* Ssrc = (d == 0) ? S0 : (d == 1) ? S1 : S2;
    const float* Tsrc = (d == 0) ? T0 : (d == 1) ? T1 : T2;

    size_t roff = (size_t)row * RDIM + sub * 4;
    float4 s_in = *(const float4*)(Ssrc + roff);
    float4 t_in = *(const float4*)(Tsrc + roff);

    int    t  = head[rid];
    float4 oS = s_in;
    float4 oT = t_in;

    if (t != 0) {
        float4 gd = *(const float4*)(Ud + roff);
        float4 rg;
        rg.x = __builtin_amdgcn_rcpf(gd.x);
        rg.y = __builtin_amdgcn_rcpf(gd.y);
        rg.z = __builtin_amdgcn_rcpf(gd.z);
        rg.w = __builtin_amdgcn_rcpf(gd.w);

        float4 sa = make_float4(0.f, 0.f, 0.f, 0.f);
        float4 ta = make_float4(0.f, 0.f, 0.f, 0.f);
        while (t != 0) {
            int idx = t - 1;
            int e = idx / 3;
            float2 aw = scal[e];
            float4 Lp = *(const float4*)(LpBuf + (size_t)e * RDIM + sub * 4);
            float cx = Lp.x * rg.x, cy = Lp.y * rg.y,
                  cz = Lp.z * rg.z, cw = Lp.w * rg.w;
            sa.x += aw.y * cx * cx;  sa.y += aw.y * cy * cy;
            sa.z += aw.y * cz * cz;  sa.w += aw.y * cw * cw;
            ta.x += (aw.x + aw.y * Lp.x) * cx;
            ta.y += (aw.x + aw.y * Lp.y) * cy;
            ta.z += (aw.x + aw.y * Lp.z) * cz;
            ta.w += (aw.x + aw.y * Lp.w) * cw;
            t = nxt[idx];
        }
        oS.x = (1.0f - STEP) * s_in.x + STEP * sa.x;
        oS.y = (1.0f - STEP) * s_in.y + STEP * sa.y;
        oS.z = (1.0f - STEP) * s_in.z + STEP * sa.z;
        oS.w = (1.0f - STEP) * s_in.w + STEP * sa.w;
        oT.x = (1.0f - STEP) * t_in.x + STEP * ta.x;
        oT.y = (1.0f - STEP) * t_in.y + STEP * ta.y;
        oT.z = (1.0f - STEP) * t_in.z + STEP * ta.z;
        oT.w = (1.0f - STEP) * t_in.w + STEP * ta.w;
    }

    size_t offS = ((size_t)d * NROW + row) * RDIM + sub * 4;
    *(float4*)(out + offS) = oS;
    *(float4*)(out + (size_t)3 * NROW * RDIM + offS) = oT;
}

// ===========================================================================
extern "C" void kernel_launch(void* const* d_in, const int* in_sizes, int n_in,
                              void* d_out, int out_size, void* d_ws, size_t ws_size,
                              hipStream_t stream)
{
    // setup_inputs() insertion order: U0,S0,T0, U1,S1,T1, U2,S2,T2, L, bv, be
    const float* U0 = (const float*)d_in[0];
    const float* S0 = (const float*)d_in[1];
    const float* T0 = (const float*)d_in[2];
    const float* U1 = (const float*)d_in[3];
    const float* S1 = (const float*)d_in[4];
    const float* T1 = (const float*)d_in[5];
    const float* U2 = (const float*)d_in[6];
    const float* S2 = (const float*)d_in[7];
    const float* T2 = (const float*)d_in[8];
    const float* L  = (const float*)d_in[9];
    const float* bv = (const float*)d_in[10];
    const int*   be = (const int*)d_in[11];

    float* out = (float*)d_out;

    const size_t rows3 = (size_t)3 * NROW;
    const size_t nxt_n = (size_t)3 * BATCH;
    const size_t bkt_n = rows3 * CAP;

    const size_t ws_fast = (2 * rows3 + nxt_n + bkt_n) * sizeof(int)
                         + (size_t)BATCH * sizeof(float2)
                         + (size_t)BATCH * RDIM * sizeof(float);   // ~43.4 MB
    const size_t ws_mid  = (rows3 + nxt_n) * sizeof(int)
                         + (size_t)BATCH * sizeof(float2)
                         + (size_t)BATCH * RDIM * sizeof(float);   // ~21.8 MB

    if (ws_size >= ws_fast) {
        // ---- fast path: bucketed CSR, burst-issue apply ----
        int*    cnt    = (int*)d_ws;
        int*    head_  = cnt + rows3;
        int*    nxt    = head_ + rows3;
        int*    bucket = nxt + nxt_n;
        float2* scal   = (float2*)(bucket + bkt_n);
        float*  LpBuf  = (float*)(scal + BATCH);

        // cnt=0 and head=0 (idx+1 encoding) in ONE memset
        hipMemsetAsync(cnt, 0, 2 * rows3 * sizeof(int), stream);

        int pblocks = (BATCH * 8 + 255) / 256;    // 4096
        em_pre_bkt<<<pblocks, 256, 0, stream>>>(U0, U1, U2, L, bv, be,
                                                cnt, head_, nxt, bucket,
                                                scal, LpBuf);

        long athreads = 3L * NROW * 8;            // 4.8M
        int  ablocks  = (int)((athreads + 255) / 256);  // 18750
        em_apply_mlp<<<ablocks, 256, 0, stream>>>(U0, U1, U2, S0, S1, S2,
                                                  T0, T1, T2, cnt, head_, nxt,
                                                  bucket, scal, LpBuf, out);
    } else if (ws_size >= ws_mid) {
        // ---- fallback: round-5 linked-list version ----
        int*    head_ = (int*)d_ws;
        int*    nxt   = head_ + rows3;
        float2* scal  = (float2*)(nxt + nxt_n);
        float*  LpBuf = (float*)(scal + BATCH);

        hipMemsetAsync(head_, 0, rows3 * sizeof(int), stream);

        int pblocks = (BATCH * 8 + 255) / 256;
        em_pre<<<pblocks, 256, 0, stream>>>(U0, U1, U2, L, bv, be,
                                            head_, nxt, scal, LpBuf);

        long athreads = 3L * NROW * 8;
        int  ablocks  = (int)((athreads + 255) / 256);
        em_apply_vec<<<ablocks, 256, 0, stream>>>(U0, U1, U2, S0, S1, S2,
                                                  T0, T1, T2, head_, nxt,
                                                  scal, LpBuf, out);
    }
}